// Round 11
// baseline (25787.415 us; speedup 1.0000x reference)
//
#include <hip/hip_runtime.h>

// SparseGPT forward on MI355X. Round 11: replicate JAX-on-ROCm-GPU fp32.
// - GEMMs: pure k-ascending single-accumulator f32 FMA (hipblaslt fp32 style).
// - exp/erf/rsqrt: OCML via expf/erff/rsqrtf (bit-identical to XLA-ROCm emission).
// - Reductions (rmsnorm mean, softmax denom): XLA-GPU row-reduce emulation:
//   512 strided thread-partials (vec2 for 1024, stride-512 for 2049) then
//   wave64 shfl_down trees (offsets 32..1) + 8-wave LDS tree, exact order.
// - abs-topk exact on f32 bits. All __fmul_rn/__fadd_rn/__builtin_fmaf.

typedef unsigned int u32;

#define TT 2048
#define DD 1024
#define HH 16
#define DMM 4096
#define VV 32000

// in-place wave64 shfl_down-tree fold over v[0..63]: offsets 32,16,8,4,2,1
__device__ __forceinline__ float tree64_lds(float* v){
  #pragma unroll
  for (int off=32; off; off>>=1)
    for (int i=0;i<off;i++) v[i] = __fadd_rn(v[i], v[i+off]);
  return v[0];
}

// ---------------- embedding: x[t] = wte[idx[t]] + wpe[t] ----------------
__global__ __launch_bounds__(256) void embed32_k(const int* __restrict__ idx,
    const float* __restrict__ wte, const float* __restrict__ wpe, float* __restrict__ x){
  int t = blockIdx.x, tid = threadIdx.x;
  int tok = idx[t];
  #pragma unroll
  for (int i=0;i<4;i++){
    int e = tid*4 + i;
    x[(size_t)t*DD + e] = __fadd_rn(wte[(size_t)tok*DD + e], wpe[(size_t)t*DD + e]);
  }
}

// ------- rmsnorm, XLA-GPU replica: vec2 partials (512) + wave trees -------
__global__ __launch_bounds__(64) void rms_xla_k(const float* __restrict__ x,
    const float* __restrict__ w, float* __restrict__ out){
  __shared__ float sq[1024];
  __shared__ float p5[512];
  __shared__ float fin[64];
  __shared__ float srt;
  int row = blockIdx.x, lane = threadIdx.x;
  const float* xr = x + (size_t)row*DD;
  for (int i=lane; i<1024; i+=64){ float v = xr[i]; sq[i] = __fmul_rn(v,v); }
  __syncthreads();
  for (int t=lane; t<512; t+=64)
    p5[t] = __fadd_rn(sq[2*t], sq[2*t+1]);          // vec2 partial
  __syncthreads();
  if (lane==0){
    for (int wv=0; wv<8; ++wv) tree64_lds(&p5[64*wv]); // per-wave shfl_down tree
    for (int i=0;i<64;i++) fin[i] = (i<8) ? p5[64*i] : 0.0f;
    float s = tree64_lds(fin);                      // cross-wave tree (zeros no-op)
    float mean = __fdiv_rn(s, 1024.0f);
    srt = rsqrtf(__fadd_rn(mean, 1e-6f));           // OCML rsqrt (XLA lax.rsqrt)
  }
  __syncthreads();
  float r = srt;
  for (int i=lane; i<1024; i+=64)
    out[(size_t)row*DD + i] = __fmul_rn(__fmul_rn(xr[i], r), w[i]);
}

// ------- GEMM, hipblaslt-fp32 replica: pure k-ascending seq FMA -------
// C[M][N] = A[M][K] * B[K][N]. One output/thread, 16x16 tile, LDS-staged.
// MODE: 0 = store, 1 = f32 += (residual), 2 = gelu (OCML erff) store.
template<int MODE>
__global__ __launch_bounds__(256) void gemm_seq_k(const float* __restrict__ A,
    const float* __restrict__ B, float* __restrict__ C, int M, int N, int K){
  __shared__ float As[16][65];
  __shared__ float Bs[64][17];
  const int tid = threadIdx.x;
  const int tr = tid >> 4, tc = tid & 15;
  const int m0 = blockIdx.y*16, n0 = blockIdx.x*16;

  float acc = 0.0f;                                  // single accumulator, whole K
  for (int kk=0; kk<K; kk+=64){
    __syncthreads();
    {
      int r = tid >> 6, c = tid & 63;                // A: 16 rows x 64 k
      #pragma unroll
      for (int it=0; it<4; ++it)
        As[r + it*4][c] = A[(size_t)(m0 + r + it*4)*K + kk + c];
      int r2 = tid >> 4, c2 = tid & 15;              // B: 64 k x 16 cols
      #pragma unroll
      for (int it=0; it<4; ++it)
        Bs[r2 + it*16][c2] = B[(size_t)(kk + r2 + it*16)*N + n0 + c2];
    }
    __syncthreads();
    #pragma unroll 8
    for (int k=0; k<64; ++k)
      acc = __builtin_fmaf(As[tr][k], Bs[k][tc], acc);
  }

  size_t off = (size_t)(m0+tr)*N + (n0+tc);
  if (MODE==0){
    C[off] = acc;
  } else if (MODE==1){
    C[off] = __fadd_rn(C[off], acc);                 // x = x + delta
  } else {
    // jax.nn.gelu exact: x * (erf(x/sqrt(2)) + 1) / 2  (pow2 scale exact)
    float t = __fdiv_rn(acc, 1.41421356f);
    float e = erff(t);                               // OCML erf_f32
    C[off] = __fmul_rn(__fmul_rn(0.5f, acc), __fadd_rn(1.0f, e));
  }
}

// ---------------- attention, XLA-ROCm replica ----------------
// Block = one (q, h), 64 lanes. Scores: seq d=0..63 FMA then *0.125f.
// Softmax: max (order-free), expf (OCML), denom = XLA row-reduce over the
// 2049-slot row [sink, s0..s2047] (stride-512 partials + wave trees),
// probs = p/denom (f32 div). PV: seq kv ascending FMA (zeros skipped: no-op).
__global__ __launch_bounds__(64) void attn_xla_k(const float* __restrict__ qkv,
    const float* __restrict__ sink, float* __restrict__ y){
  __shared__ float Ql[64];
  __shared__ float arr[2049];
  __shared__ float p5[512];
  __shared__ float fin[64];
  __shared__ float sden;
  const int lane = threadIdx.x;
  const int q = blockIdx.x, h = blockIdx.y;
  const float snk = sink[h];

  Ql[lane] = qkv[(size_t)q*3072 + h*64 + lane];
  for (int i=lane; i<2049; i+=64) arr[i] = 0.0f;
  __syncthreads();

  float mloc = -3.402823466e38f;
  for (int kv=lane; kv<=q; kv+=64){
    const float* kr = qkv + (size_t)kv*3072 + 1024 + h*64;
    float s = 0.0f;
    #pragma unroll 8
    for (int d=0; d<64; ++d) s = __builtin_fmaf(Ql[d], kr[d], s);
    s = __fmul_rn(s, 0.125f);
    arr[1+kv] = s;
    mloc = fmaxf(mloc, s);
  }
  #pragma unroll
  for (int o=1;o<64;o<<=1) mloc = fmaxf(mloc, __shfl_xor(mloc, o, 64));
  float m = fmaxf(mloc, snk);
  __syncthreads();

  for (int kv=lane; kv<=q; kv+=64)
    arr[1+kv] = expf(__fsub_rn(arr[1+kv], m));       // OCML exp_f32
  if (lane==0) arr[0] = expf(__fsub_rn(snk, m));
  __syncthreads();

  // XLA row-reduce: 512 stride partials over 2049, then wave trees
  for (int t=lane; t<512; t+=64){
    float a = 0.0f;
    for (int i=t; i<2049; i+=512) a = __fadd_rn(a, arr[i]);
    p5[t] = a;
  }
  __syncthreads();
  if (lane==0){
    for (int wv=0; wv<8; ++wv) tree64_lds(&p5[64*wv]);
    for (int i=0;i<64;i++) fin[i] = (i<8) ? p5[64*i] : 0.0f;
    sden = tree64_lds(fin);
  }
  __syncthreads();
  float den = sden;
  for (int kv=lane; kv<=q; kv+=64)
    arr[1+kv] = __fdiv_rn(arr[1+kv], den);           // probs
  __syncthreads();

  float acc = 0.0f;
  const float* vb = qkv + 2048 + h*64 + lane;
  for (int kv=0; kv<=q; ++kv)
    acc = __builtin_fmaf(arr[1+kv], vb[(size_t)kv*3072], acc);
  y[(size_t)q*DD + h*64 + lane] = acc;
}

// -------- abs top-k on f32 bits: exact radix select; zero in place --------
__global__ __launch_bounds__(256) void topk32_k(float* __restrict__ h,
    const int* __restrict__ kptr){
  const int row = blockIdx.x, tid = threadIdx.x;
  __shared__ int suf[256];
  __shared__ int s_sel, s_k;
  float* hr = h + (size_t)row*DMM;
  int kk = kptr[0];
  u32 prefix = 0u;
  for (int pass=0; pass<4; pass++){
    int shift = 24 - 8*pass;
    u32 hi_mask = pass ? (0xFFFFFFFFu << (shift+8)) : 0u;
    suf[tid] = 0;
    __syncthreads();
    for (int i=0;i<16;i++){
      u32 b = __float_as_uint(hr[tid + 256*i]) & 0x7fffffffu;
      if ((b & hi_mask) == prefix) atomicAdd(&suf[(b>>shift)&255], 1);
    }
    __syncthreads();
    for (int s=1;s<256;s<<=1){
      int v2 = (tid+s<256) ? suf[tid+s] : 0;
      __syncthreads();
      suf[tid] += v2;
      __syncthreads();
    }
    int nxt = (tid<255) ? suf[tid+1] : 0;
    if (suf[tid] >= kk && nxt < kk){ s_sel = tid; s_k = kk - nxt; }
    __syncthreads();
    prefix |= ((u32)s_sel) << shift;
    kk = s_k;
    __syncthreads();
  }
  for (int i=0;i<16;i++){
    int e = tid + 256*i;
    u32 b = __float_as_uint(hr[e]) & 0x7fffffffu;
    if (b < prefix) hr[e] = 0.0f;   // keep |x| >= kth-largest (ties kept)
  }
}

// ---------------- host launcher ----------------
extern "C" void kernel_launch(void* const* d_in, const int* in_sizes, int n_in,
                              void* d_out, int out_size, void* d_ws, size_t ws_size,
                              hipStream_t stream){
  const int*   idx  = (const int*)  d_in[0];
  const float* wte  = (const float*)d_in[1];
  const float* wpe  = (const float*)d_in[2];
  const float* ln1  = (const float*)d_in[3];
  const float* ln2  = (const float*)d_in[4];
  const float* Wa   = (const float*)d_in[5];
  const float* Wap  = (const float*)d_in[6];
  const float* Wf   = (const float*)d_in[7];
  const float* Wp   = (const float*)d_in[8];
  const float* sink = (const float*)d_in[9];
  const float* lnf  = (const float*)d_in[10];
  const float* lmw  = (const float*)d_in[11];
  const int*   kptr = (const int*)  d_in[12];
  (void)in_sizes; (void)n_in; (void)out_size; (void)ws_size;

  // ---- workspace: 80 MB, all fp32, no aliasing ----
  char* w = (char*)d_ws;
  float* x   = (float*)(w);                 // [0, 8M)
  float* xn  = (float*)(w + 8388608);       // [8M, 16M)
  float* qkv = (float*)(w + 16777216);      // [16M, 40M)
  float* y   = (float*)(w + 41943040);      // [40M, 48M)
  float* h   = (float*)(w + 50331648);      // [48M, 80M)

  embed32_k<<<TT, 256, 0, stream>>>(idx, wte, wpe, x);

  for (int l=0; l<4; l++){
    rms_xla_k<<<TT, 64, 0, stream>>>(x, ln1 + l*DD, xn);
    gemm_seq_k<0><<<dim3(3072/16, TT/16), 256, 0, stream>>>(xn, Wa + (size_t)l*1024*3072, qkv, TT, 3072, 1024);
    attn_xla_k<<<dim3(TT, HH), 64, 0, stream>>>(qkv, sink + l*HH, y);
    gemm_seq_k<1><<<dim3(1024/16, TT/16), 256, 0, stream>>>(y, Wap + (size_t)l*1024*1024, x, TT, 1024, 1024);
    rms_xla_k<<<TT, 64, 0, stream>>>(x, ln2 + l*DD, xn);
    gemm_seq_k<2><<<dim3(4096/16, TT/16), 256, 0, stream>>>(xn, Wf + (size_t)l*1024*4096, h, TT, 4096, 1024);
    topk32_k<<<TT, 256, 0, stream>>>(h, kptr);
    gemm_seq_k<1><<<dim3(1024/16, TT/16), 256, 0, stream>>>(h, Wp + (size_t)l*4096*1024, x, TT, 1024, 4096);
  }

  rms_xla_k<<<TT, 64, 0, stream>>>(x, lnf, xn);
  gemm_seq_k<0><<<dim3(VV/16, TT/16), 256, 0, stream>>>(xn, lmw, (float*)d_out, TT, VV, 1024);
}

// Round 12
// 12999.286 us; speedup vs baseline: 1.9838x; 1.9838x over previous
//
#include <hip/hip_runtime.h>

// SparseGPT forward on MI355X. Round 12: same bit-exact arithmetic as the
// PASSING Round 11 (k-ascending single-acc fp32 FMA GEMM, OCML expf/erff/
// rsqrtf, XLA-style reductions) -- but the GEMM is re-tiled for throughput:
// 128x128 tile, BK=32, 8x8 outputs/thread, float4 LDS/global, conflict-free
// layout. Per-element FMA order is unchanged => output is bit-identical.

typedef unsigned int u32;

#define TT 2048
#define DD 1024
#define HH 16
#define DMM 4096
#define VV 32000

// in-place wave64 shfl_down-tree fold over v[0..63]: offsets 32,16,8,4,2,1
__device__ __forceinline__ float tree64_lds(float* v){
  #pragma unroll
  for (int off=32; off; off>>=1)
    for (int i=0;i<off;i++) v[i] = __fadd_rn(v[i], v[i+off]);
  return v[0];
}

// ---------------- embedding: x[t] = wte[idx[t]] + wpe[t] ----------------
__global__ __launch_bounds__(256) void embed32_k(const int* __restrict__ idx,
    const float* __restrict__ wte, const float* __restrict__ wpe, float* __restrict__ x){
  int t = blockIdx.x, tid = threadIdx.x;
  int tok = idx[t];
  #pragma unroll
  for (int i=0;i<4;i++){
    int e = tid*4 + i;
    x[(size_t)t*DD + e] = __fadd_rn(wte[(size_t)tok*DD + e], wpe[(size_t)t*DD + e]);
  }
}

// ------- rmsnorm, XLA-GPU replica: vec2 partials (512) + wave trees -------
__global__ __launch_bounds__(64) void rms_xla_k(const float* __restrict__ x,
    const float* __restrict__ w, float* __restrict__ out){
  __shared__ float sq[1024];
  __shared__ float p5[512];
  __shared__ float fin[64];
  __shared__ float srt;
  int row = blockIdx.x, lane = threadIdx.x;
  const float* xr = x + (size_t)row*DD;
  for (int i=lane; i<1024; i+=64){ float v = xr[i]; sq[i] = __fmul_rn(v,v); }
  __syncthreads();
  for (int t=lane; t<512; t+=64)
    p5[t] = __fadd_rn(sq[2*t], sq[2*t+1]);          // vec2 partial
  __syncthreads();
  if (lane==0){
    for (int wv=0; wv<8; ++wv) tree64_lds(&p5[64*wv]); // per-wave shfl_down tree
    for (int i=0;i<64;i++) fin[i] = (i<8) ? p5[64*i] : 0.0f;
    float s = tree64_lds(fin);                      // cross-wave tree (zeros no-op)
    float mean = __fdiv_rn(s, 1024.0f);
    srt = rsqrtf(__fadd_rn(mean, 1e-6f));           // OCML rsqrt (XLA lax.rsqrt)
  }
  __syncthreads();
  float r = srt;
  for (int i=lane; i<1024; i+=64)
    out[(size_t)row*DD + i] = __fmul_rn(__fmul_rn(xr[i], r), w[i]);
}

// ------- GEMM, fast tiling, SAME per-element math as R11 -------
// C[M][N] = A[M][K] * B[K][N]; each output = strict k-ascending f32 FMA chain.
// 128x128 tile, BK=32, 256 threads (16x16), 8x8 outputs/thread: thread (tr,tc)
// owns rows {4tr+i, 64+4tr+i} cols {4tc+j, 64+4tc+j} -> all LDS reads are
// 16B-aligned float4, broadcast or stride-16B (conflict-free).
// MODE: 0 = store, 1 = f32 += (residual), 2 = gelu (OCML erff) store.
template<int MODE>
__global__ __launch_bounds__(256) void gemm_fast_k(const float* __restrict__ A,
    const float* __restrict__ B, float* __restrict__ C, int M, int N, int K){
  __shared__ float As[32][132];   // [k][m], +4 pad
  __shared__ float Bs[32][132];   // [k][n], +4 pad
  const int tid = threadIdx.x;
  const int tr = tid >> 4, tc = tid & 15;
  const int m0 = blockIdx.y*128, n0 = blockIdx.x*128;

  float acc[8][8];
  #pragma unroll
  for (int i=0;i<8;i++)
    #pragma unroll
    for (int j=0;j<8;j++) acc[i][j] = 0.0f;

  for (int kk=0; kk<K; kk+=32){
    __syncthreads();
    #pragma unroll
    for (int it=0; it<4; ++it){            // A: 128 rows x 32 k -> As[k][m] (transpose)
      int id = it*256 + tid;
      int row = id >> 3, f4 = id & 7;
      float4 v = *(const float4*)&A[(size_t)(m0+row)*K + kk + 4*f4];
      As[4*f4+0][row] = v.x; As[4*f4+1][row] = v.y;
      As[4*f4+2][row] = v.z; As[4*f4+3][row] = v.w;
    }
    #pragma unroll
    for (int it=0; it<4; ++it){            // B: 32 k x 128 n -> Bs[k][n] (direct)
      int id = it*256 + tid;
      int r = id >> 5, f4 = id & 31;
      float4 v = *(const float4*)&B[(size_t)(kk+r)*N + n0 + 4*f4];
      *(float4*)&Bs[r][4*f4] = v;
    }
    __syncthreads();
    #pragma unroll 4
    for (int k=0; k<32; ++k){
      float4 a0 = *(const float4*)&As[k][4*tr];
      float4 a1 = *(const float4*)&As[k][64 + 4*tr];
      float4 b0 = *(const float4*)&Bs[k][4*tc];
      float4 b1 = *(const float4*)&Bs[k][64 + 4*tc];
      float av[8] = {a0.x,a0.y,a0.z,a0.w, a1.x,a1.y,a1.z,a1.w};
      float bv[8] = {b0.x,b0.y,b0.z,b0.w, b1.x,b1.y,b1.z,b1.w};
      #pragma unroll
      for (int i=0;i<8;i++)
        #pragma unroll
        for (int j=0;j<8;j++)
          acc[i][j] = __builtin_fmaf(av[i], bv[j], acc[i][j]);
    }
  }
  #pragma unroll
  for (int i=0;i<8;i++){
    int row = m0 + (i>>2)*64 + 4*tr + (i&3);
    #pragma unroll
    for (int jq=0;jq<2;jq++){
      size_t off = (size_t)row*N + n0 + jq*64 + 4*tc;
      #pragma unroll
      for (int e=0;e<4;e++){
        float vv = acc[i][jq*4+e];
        if (MODE==0){
          C[off+e] = vv;
        } else if (MODE==1){
          C[off+e] = __fadd_rn(C[off+e], vv);        // x = x + delta
        } else {
          float t = __fdiv_rn(vv, 1.41421356f);      // jax.nn.gelu exact
          float g = erff(t);                         // OCML erf_f32
          C[off+e] = __fmul_rn(__fmul_rn(0.5f, vv), __fadd_rn(1.0f, g));
        }
      }
    }
  }
}

// ---------------- attention, XLA-ROCm replica (unchanged from R11) ----------------
__global__ __launch_bounds__(64) void attn_xla_k(const float* __restrict__ qkv,
    const float* __restrict__ sink, float* __restrict__ y){
  __shared__ float Ql[64];
  __shared__ float arr[2049];
  __shared__ float p5[512];
  __shared__ float fin[64];
  __shared__ float sden;
  const int lane = threadIdx.x;
  const int q = blockIdx.x, h = blockIdx.y;
  const float snk = sink[h];

  Ql[lane] = qkv[(size_t)q*3072 + h*64 + lane];
  for (int i=lane; i<2049; i+=64) arr[i] = 0.0f;
  __syncthreads();

  float mloc = -3.402823466e38f;
  for (int kv=lane; kv<=q; kv+=64){
    const float* kr = qkv + (size_t)kv*3072 + 1024 + h*64;
    float s = 0.0f;
    #pragma unroll 8
    for (int d=0; d<64; ++d) s = __builtin_fmaf(Ql[d], kr[d], s);
    s = __fmul_rn(s, 0.125f);
    arr[1+kv] = s;
    mloc = fmaxf(mloc, s);
  }
  #pragma unroll
  for (int o=1;o<64;o<<=1) mloc = fmaxf(mloc, __shfl_xor(mloc, o, 64));
  float m = fmaxf(mloc, snk);
  __syncthreads();

  for (int kv=lane; kv<=q; kv+=64)
    arr[1+kv] = expf(__fsub_rn(arr[1+kv], m));       // OCML exp_f32
  if (lane==0) arr[0] = expf(__fsub_rn(snk, m));
  __syncthreads();

  for (int t=lane; t<512; t+=64){                    // XLA row-reduce
    float a = 0.0f;
    for (int i=t; i<2049; i+=512) a = __fadd_rn(a, arr[i]);
    p5[t] = a;
  }
  __syncthreads();
  if (lane==0){
    for (int wv=0; wv<8; ++wv) tree64_lds(&p5[64*wv]);
    for (int i=0;i<64;i++) fin[i] = (i<8) ? p5[64*i] : 0.0f;
    sden = tree64_lds(fin);
  }
  __syncthreads();
  float den = sden;
  for (int kv=lane; kv<=q; kv+=64)
    arr[1+kv] = __fdiv_rn(arr[1+kv], den);           // probs
  __syncthreads();

  float acc = 0.0f;
  const float* vb = qkv + 2048 + h*64 + lane;
  for (int kv=0; kv<=q; ++kv)
    acc = __builtin_fmaf(arr[1+kv], vb[(size_t)kv*3072], acc);
  y[(size_t)q*DD + h*64 + lane] = acc;
}

// -------- abs top-k on f32 bits: exact radix select; zero in place --------
__global__ __launch_bounds__(256) void topk32_k(float* __restrict__ h,
    const int* __restrict__ kptr){
  const int row = blockIdx.x, tid = threadIdx.x;
  __shared__ int suf[256];
  __shared__ int s_sel, s_k;
  float* hr = h + (size_t)row*DMM;
  int kk = kptr[0];
  u32 prefix = 0u;
  for (int pass=0; pass<4; pass++){
    int shift = 24 - 8*pass;
    u32 hi_mask = pass ? (0xFFFFFFFFu << (shift+8)) : 0u;
    suf[tid] = 0;
    __syncthreads();
    for (int i=0;i<16;i++){
      u32 b = __float_as_uint(hr[tid + 256*i]) & 0x7fffffffu;
      if ((b & hi_mask) == prefix) atomicAdd(&suf[(b>>shift)&255], 1);
    }
    __syncthreads();
    for (int s=1;s<256;s<<=1){
      int v2 = (tid+s<256) ? suf[tid+s] : 0;
      __syncthreads();
      suf[tid] += v2;
      __syncthreads();
    }
    int nxt = (tid<255) ? suf[tid+1] : 0;
    if (suf[tid] >= kk && nxt < kk){ s_sel = tid; s_k = kk - nxt; }
    __syncthreads();
    prefix |= ((u32)s_sel) << shift;
    kk = s_k;
    __syncthreads();
  }
  for (int i=0;i<16;i++){
    int e = tid + 256*i;
    u32 b = __float_as_uint(hr[e]) & 0x7fffffffu;
    if (b < prefix) hr[e] = 0.0f;   // keep |x| >= kth-largest (ties kept)
  }
}

// ---------------- host launcher ----------------
extern "C" void kernel_launch(void* const* d_in, const int* in_sizes, int n_in,
                              void* d_out, int out_size, void* d_ws, size_t ws_size,
                              hipStream_t stream){
  const int*   idx  = (const int*)  d_in[0];
  const float* wte  = (const float*)d_in[1];
  const float* wpe  = (const float*)d_in[2];
  const float* ln1  = (const float*)d_in[3];
  const float* ln2  = (const float*)d_in[4];
  const float* Wa   = (const float*)d_in[5];
  const float* Wap  = (const float*)d_in[6];
  const float* Wf   = (const float*)d_in[7];
  const float* Wp   = (const float*)d_in[8];
  const float* sink = (const float*)d_in[9];
  const float* lnf  = (const float*)d_in[10];
  const float* lmw  = (const float*)d_in[11];
  const int*   kptr = (const int*)  d_in[12];
  (void)in_sizes; (void)n_in; (void)out_size; (void)ws_size;

  // ---- workspace: 80 MB, all fp32, no aliasing ----
  char* w = (char*)d_ws;
  float* x   = (float*)(w);                 // [0, 8M)
  float* xn  = (float*)(w + 8388608);       // [8M, 16M)
  float* qkv = (float*)(w + 16777216);      // [16M, 40M)
  float* y   = (float*)(w + 41943040);      // [40M, 48M)
  float* h   = (float*)(w + 50331648);      // [48M, 80M)

  embed32_k<<<TT, 256, 0, stream>>>(idx, wte, wpe, x);

  for (int l=0; l<4; l++){
    rms_xla_k<<<TT, 64, 0, stream>>>(x, ln1 + l*DD, xn);
    gemm_fast_k<0><<<dim3(3072/128, TT/128), 256, 0, stream>>>(xn, Wa + (size_t)l*1024*3072, qkv, TT, 3072, 1024);
    attn_xla_k<<<dim3(TT, HH), 64, 0, stream>>>(qkv, sink + l*HH, y);
    gemm_fast_k<1><<<dim3(1024/128, TT/128), 256, 0, stream>>>(y, Wap + (size_t)l*1024*1024, x, TT, 1024, 1024);
    rms_xla_k<<<TT, 64, 0, stream>>>(x, ln2 + l*DD, xn);
    gemm_fast_k<2><<<dim3(4096/128, TT/128), 256, 0, stream>>>(xn, Wf + (size_t)l*1024*4096, h, TT, 4096, 1024);
    topk32_k<<<TT, 256, 0, stream>>>(h, kptr);
    gemm_fast_k<1><<<dim3(1024/128, TT/128), 256, 0, stream>>>(h, Wp + (size_t)l*4096*1024, x, TT, 1024, 4096);
  }

  rms_xla_k<<<TT, 64, 0, stream>>>(x, lnf, xn);
  gemm_fast_k<0><<<dim3(VV/128, TT/128), 256, 0, stream>>>(xn, lmw, (float*)d_out, TT, VV, 1024);
}